// Round 9
// baseline (434.740 us; speedup 1.0000x reference)
//
#include <hip/hip_runtime.h>

#define LL 256   // sequence length
#define EE 64    // embed dim
#define HH 64    // hidden dim
#define GG 256   // 4*H gates
#define NSEQ 8   // sequences per block; tile rows 0-7 fwd h, 8-15 bwd h
#define VV 6000  // vocab
#define ROWP 72  // padded LDS row stride in bf16 elems (144 B, 16B-aligned)
#define VBLK 375 // phase-1 blocks per direction (6000/16)

typedef __bf16 bf16_t;
typedef bf16_t bf16x8 __attribute__((ext_vector_type(8)));
typedef float  f32x4  __attribute__((ext_vector_type(4)));

union BfPack {
    unsigned short u[8];
    bf16x8 v;
};

__device__ __forceinline__ unsigned short f2bf(float f) {
    return __builtin_bit_cast(unsigned short, (__bf16)f);
}

#define LOG2E 1.44269504088896340736f

// exp2+rcp activations (R1: removed IEEE div sequences). Inf-safe both ends.
__device__ __forceinline__ float sigm(float x) {
    float e = __builtin_amdgcn_exp2f(-LOG2E * x);          // e^{-x}
    return __builtin_amdgcn_rcpf(1.0f + e);
}
__device__ __forceinline__ float tanh_fast(float x) {
    float e = __builtin_amdgcn_exp2f((2.0f * LOG2E) * x);  // e^{2x}
    return 1.0f - 2.0f * __builtin_amdgcn_rcpf(e + 1.0f);
}

// lgkm-only barrier (R0->R1: 567->415 us): cross-wave deps are LDS-only;
// out-stores and pre-gathers stay in flight across it (vmcnt untouched).
#define LGKM_BARRIER() asm volatile("s_waitcnt lgkmcnt(0)\n\ts_barrier" ::: "memory")

// ---------------- phase 1: embedPre[dir][v][swz(g)] = bf16(embed@Wk + b) ----
// x_t @ Wk == (embed @ Wk)[id] : the whole input projection is a table.
// bf16 table (R5: FETCH 375->138 MB). Swizzle: pos = ((g>>4)&3)*64+(g&15)*4+
// (g>>6): phase-2 lane (w,quad,l15) reads its 4 gate values per seq-row as
// ONE dwordx2 at elem [id*256 + w*64 + l15*4].
__global__ __launch_bounds__(256)
void embed_pre_kernel(const float* __restrict__ embed,
                      const float* __restrict__ Wk_f, const float* __restrict__ b_f,
                      const float* __restrict__ Wk_b, const float* __restrict__ b_b,
                      unsigned short* __restrict__ pre)
{
    const int bid = blockIdx.x;
    const int dir = bid / VBLK;
    const int v0  = (bid % VBLK) * 16;
    const float* Wk = dir ? Wk_b : Wk_f;
    const float* bv = dir ? b_b  : b_f;
    unsigned short* dst = pre + (size_t)dir * VV * GG;

    const int tid = threadIdx.x;
    const int r   = tid >> 4;    // v-row 0..15
    const int cg  = tid & 15;    // col residue; thread owns g = k*16+cg

    __shared__ float sW[16][GG];   // 16 KB per E-chunk
    __shared__ float sE[16][17];   // 16 rows x 16 e, padded

    float acc[16];
    #pragma unroll
    for (int k = 0; k < 16; ++k) acc[k] = 0.f;

    for (int ec = 0; ec < 4; ++ec) {
        {   // stage Wk rows ec*16..+15 (coalesced float4) + embed chunk
            int er = tid >> 4;
            int c0 = (tid & 15) * 16;
            const float* src = &Wk[(size_t)(ec * 16 + er) * GG + c0];
            *(float4*)&sW[er][c0 + 0]  = *(const float4*)(src + 0);
            *(float4*)&sW[er][c0 + 4]  = *(const float4*)(src + 4);
            *(float4*)&sW[er][c0 + 8]  = *(const float4*)(src + 8);
            *(float4*)&sW[er][c0 + 12] = *(const float4*)(src + 12);
            sE[er][tid & 15] = embed[(size_t)(v0 + er) * EE + ec * 16 + (tid & 15)];
        }
        __syncthreads();
        #pragma unroll
        for (int e = 0; e < 16; ++e) {
            float xe = sE[r][e];
            #pragma unroll
            for (int k = 0; k < 16; ++k)
                acc[k] += xe * sW[e][k * 16 + cg];   // 16 consecutive banks, CF
        }
        __syncthreads();
    }
    #pragma unroll
    for (int a = 0; a < 4; ++a) {
        ushort4 pk;
        pk.x = f2bf(acc[a]      + bv[(a)      * 16 + cg]);
        pk.y = f2bf(acc[a + 4]  + bv[(a + 4)  * 16 + cg]);
        pk.z = f2bf(acc[a + 8]  + bv[(a + 8)  * 16 + cg]);
        pk.w = f2bf(acc[a + 12] + bv[(a + 12) * 16 + cg]);
        *(ushort4*)&dst[(size_t)(v0 + r) * GG + a * 64 + cg * 4] = pk;
    }
}

// ---------------- phase 2: dual-direction recurrence ------------------------
// One block = 8 seqs x BOTH dirs, 4 waves, 256 threads, grid=256 (1 block/CU).
// MFMA A-tile: rows 0-7 = h_fwd, rows 8-15 = h_bwd (same 8 seqs). A-frags are
// read ONCE per step; MFMAs run twice -- B=Wr_f (rows 0-7 valid) and B=Wr_b
// (rows 8-15 valid); quads 0-1 keep the fwd acc, quads 2-3 the bwd acc.
// Two independent dependency chains per wave fill each other's stalls (R5/R6:
// 1 chain -> 52% VALUBusy, 48% unfillable; R6 proved wave-level TLP can't
// fill it because block barriers lock-step the waves).
__global__ __launch_bounds__(256, 1)
void bilstm_mfma(const int* __restrict__ ids,
                 const float* __restrict__ Wr_f, const float* __restrict__ Wr_b,
                 const unsigned short* __restrict__ pre,
                 float* __restrict__ out)
{
    const int grp = blockIdx.x;         // 0..255: seq group, both dirs
    const int n0  = grp * NSEQ;
    const int tid  = threadIdx.x;
    const int w    = tid >> 6;          // 0..3: gate col-group
    const int lane = tid & 63;
    const int l15  = lane & 15;
    const int quad = lane >> 4;
    const int j    = w * 16 + l15;      // gate sub-index in [0,64)
    const int dirq = quad >> 1;         // 0: rows 0-7 (fwd), 1: rows 8-15 (bwd)
    const int seqb = (quad & 1) * 4;    // this quad's base seq (0 or 4)

    const unsigned short* preT = pre + (size_t)dirq * VV * GG;  // own-dir table
    const int coff = w * 64 + l15 * 4;  // lane's fixed swizzled elem offset

    __shared__ __align__(16) short s_h[2][16][ROWP];    // 4.5 KB
    __shared__ int s_ids[NSEQ][LL + 1];                 // 8.2 KB

    // stage ids (coalesced)
    for (int p = tid; p < NSEQ * LL; p += 256) {
        int m = p >> 8, t = p & 255;
        s_ids[m][t] = ids[(size_t)(n0 + m) * LL + t];
    }
    // zero both h buffers (h0 = 0 for both dirs)
    for (int p = tid; p < 2 * 16 * ROWP; p += 256)
        (&s_h[0][0][0])[p] = 0;

    __syncthreads();

    // B-fragments for BOTH dirs (K=64): lane holds B[k=kc*32+quad*8+e][l15]
    bf16x8 bfrag[2][4][2];   // [dir][gate tt][k-chunk]
    #pragma unroll
    for (int d = 0; d < 2; ++d) {
        const float* Wr = d ? Wr_b : Wr_f;
        #pragma unroll
        for (int tt = 0; tt < 4; ++tt) {
            int g = tt * 64 + j;
            #pragma unroll
            for (int kc = 0; kc < 2; ++kc) {
                BfPack pk;
                #pragma unroll
                for (int e = 0; e < 8; ++e) {
                    int kg = kc * 32 + quad * 8 + e;
                    pk.u[e] = f2bf(Wr[(size_t)kg * GG + g]);
                }
                bfrag[d][tt][kc] = pk.v;
            }
        }
    }

    // depth-2 ping-pong P buffers; lane gathers its own-dir rows at own-dir time
    uint2 PA[4], PB[4];
    {
        int tA = dirq ? (LL - 1) : 0;
        int tB = dirq ? (LL - 2) : 1;
        #pragma unroll
        for (int r = 0; r < 4; ++r) {
            PA[r] = *(const uint2*)&preT[(size_t)s_ids[seqb + r][tA] * GG + coff];
            PB[r] = *(const uint2*)&preT[(size_t)s_ids[seqb + r][tB] * GG + coff];
        }
    }

    float c[4] = {0.f, 0.f, 0.f, 0.f};   // cell state, rows quad*4 + r

    // out pointers: lane's 4 rows are all one dir; advance +-256 f32/step
    const int tstep = dirq ? -(2 * HH) : (2 * HH);
    float* optr[4];
    {
        const int t0 = dirq ? (LL - 1) : 0;
        #pragma unroll
        for (int r = 0; r < 4; ++r)
            optr[r] = out + ((size_t)(n0 + seqb + r) * LL + t0) * (2 * HH) + dirq * HH + j;
    }

    auto do_step = [&](int ts, uint2 (&P)[4]) {
        const int rb = ts & 1, wb = (ts + 1) & 1;

        // A-frags read once, feed BOTH dir MFMA sets (ds_read_b128 x2)
        bf16x8 ah0 = *(const bf16x8*)&s_h[rb][l15][quad * 8];
        bf16x8 ah1 = *(const bf16x8*)&s_h[rb][l15][32 + quad * 8];

        // consume P (loaded 2 steps ago): bf16->f32 + free 4x4 transpose.
        // Lane's cIn rows are its own-dir rows -> valid seed in the MFMA
        // whose output this lane keeps; garbage-but-finite in the other.
        f32x4 cIn[4];
        #pragma unroll
        for (int r = 0; r < 4; ++r) {
            cIn[0][r] = __uint_as_float(P[r].x << 16);
            cIn[1][r] = __uint_as_float(P[r].x & 0xffff0000u);
            cIn[2][r] = __uint_as_float(P[r].y << 16);
            cIn[3][r] = __uint_as_float(P[r].y & 0xffff0000u);
        }
        // branchless refill for ts+2 (clamped tail), own-dir time index
        {
            int tn = dirq ? (LL - 3 - ts) : (ts + 2);
            tn = tn < 0 ? 0 : (tn > LL - 1 ? LL - 1 : tn);
            #pragma unroll
            for (int r = 0; r < 4; ++r)
                P[r] = *(const uint2*)&preT[(size_t)s_ids[seqb + r][tn] * GG + coff];
        }

        // two independent 2-deep MFMA chains per gate: fwd (rows 0-7 valid)
        // and bwd (rows 8-15 valid) -- 16 MFMAs, 2 chains' stalls interleave
        f32x4 accF[4], accB[4];
        #pragma unroll
        for (int tt = 0; tt < 4; ++tt) {
            f32x4 af = __builtin_amdgcn_mfma_f32_16x16x32_bf16(ah0, bfrag[0][tt][0], cIn[tt], 0, 0, 0);
            accF[tt]  = __builtin_amdgcn_mfma_f32_16x16x32_bf16(ah1, bfrag[0][tt][1], af, 0, 0, 0);
            f32x4 ab = __builtin_amdgcn_mfma_f32_16x16x32_bf16(ah0, bfrag[1][tt][0], cIn[tt], 0, 0, 0);
            accB[tt]  = __builtin_amdgcn_mfma_f32_16x16x32_bf16(ah1, bfrag[1][tt][1], ab, 0, 0, 0);
        }

        // keep own-dir acc (16 cndmasks), then gate math on 4 rows
        #pragma unroll
        for (int r = 0; r < 4; ++r) {
            float zi = dirq ? accB[0][r] : accF[0][r];
            float zf = dirq ? accB[1][r] : accF[1][r];
            float zg = dirq ? accB[2][r] : accF[2][r];
            float zo = dirq ? accB[3][r] : accF[3][r];
            float ig = sigm(zi);
            float fg = sigm(zf);
            float gg = tanh_fast(zg);
            float og = sigm(zo);
            c[r] = fg * c[r] + ig * gg;
            float hh = og * tanh_fast(c[r]);
            *optr[r] = hh;                       // plain store: fast L2 ack
            optr[r] += tstep;
            s_h[wb][quad * 4 + r][j] = (short)f2bf(hh);
        }

        // orders LDS h-writes before next step's reads; no vmcnt drain
        LGKM_BARRIER();
    };

    for (int ts = 0; ts < LL; ts += 2) {
        do_step(ts,     PA);
        do_step(ts + 1, PB);
    }
}

extern "C" void kernel_launch(void* const* d_in, const int* in_sizes, int n_in,
                              void* d_out, int out_size, void* d_ws, size_t ws_size,
                              hipStream_t stream) {
    const int*   ids   = (const int*)d_in[0];
    const float* embed = (const float*)d_in[1];
    const float* Wk_f  = (const float*)d_in[2];
    const float* Wr_f  = (const float*)d_in[3];
    const float* b_f   = (const float*)d_in[4];
    const float* Wk_b  = (const float*)d_in[5];
    const float* Wr_b  = (const float*)d_in[6];
    const float* b_b   = (const float*)d_in[7];
    float* out = (float*)d_out;
    unsigned short* pre = (unsigned short*)d_ws;   // 2*6000*256*2 B = 6.1 MB

    embed_pre_kernel<<<dim3(2 * VBLK), dim3(256), 0, stream>>>(
        embed, Wk_f, b_f, Wk_b, b_b, pre);

    bilstm_mfma<<<dim3(256), dim3(256), 0, stream>>>(ids, Wr_f, Wr_b, pre, out);
}